// Round 7
// baseline (670.146 us; speedup 1.0000x reference)
//
#include <hip/hip_runtime.h>
#include <hip/hip_fp16.h>

typedef int v4i __attribute__((ext_vector_type(4)));

#define AS1C(p) ((const __attribute__((address_space(1))) void*)(p))
#define AS3(p)  ((__attribute__((address_space(3))) void*)(p))
#define BARRIER() do { __builtin_amdgcn_s_barrier(); asm volatile("" ::: "memory"); } while (0)

__device__ __forceinline__ void fence_vm(int n) {
  if (n >= 4)      asm volatile("s_waitcnt vmcnt(4)" ::: "memory");
  else if (n >= 2) asm volatile("s_waitcnt vmcnt(2)" ::: "memory");
  else             asm volatile("s_waitcnt vmcnt(0)" ::: "memory");
}

// ---------------------------------------------------------------------------
// int8 GEMM, C = A[M,K]*B[N,K]^T. BN=256, BM in {256,128}. 8 waves (2M x 4N).
// A-fragments loaded DIRECTLY global->VGPR (per-lane contiguous 16B; 1-step
// register prefetch, static double-buffer via unroll-2). Only B goes through
// LDS (ring-4 x 16KB, 16B-slot XOR swizzle — 0 conflicts r2-r6).
// Rationale: i8's K-density makes the old A+B LDS path demand ~110 B/cyc/CU
// (reads+writes) vs ~85-128 B/cyc service — LDS BW was the invariant wall.
// Now LDS carries 48KB/K-step (~37 B/cyc at full MFMA rate).
// One fence per iter: issue A(t+1) then B(t+3); vmcnt(2) => A(t)+B(t) done.
// EPI 0: fc1 (dequant+bias -> fp16 -> GELU -> gout fp16 + atomicMax amax)
// EPI 1: fc2 (dequant with fp16(amax/127)+bias -> fp16-rounded f32 out)
// ---------------------------------------------------------------------------
template <int EPI, int BM>
__launch_bounds__(512, 1)
__global__ void gemm_areg(const signed char* __restrict__ A, const signed char* __restrict__ Bw,
                          int M, int N, int K,
                          const float* __restrict__ scale_tok, const float* __restrict__ wsc,
                          const float* __restrict__ bias,
                          __half* __restrict__ gout, unsigned int* __restrict__ amax,
                          float* __restrict__ fout) {
  constexpr int MI = BM / 32;             // A frags per wave (8 / 4)
  __shared__ __align__(16) char smem[4 * 16384];   // B ring: 4 slots x 16KB

  const int tid = threadIdx.x;
  const int lane = tid & 63, wave = tid >> 6;
  const int wavem = wave >> 2, waven = wave & 3;
  const int lh = lane & 15;

  // column-chunked bijective XCD swizzle (r6: FETCH 190->86MB, keep)
  const int gy = gridDim.y;
  int lid;
  {
    const int o = blockIdx.y * gridDim.x + blockIdx.x;
    const int nwg = gridDim.x * gy;
    const int q = nwg >> 3, r = nwg & 7;
    const int x = o & 7, p = o >> 3;
    lid = (x < r ? x * (q + 1) : r * (q + 1) + (x - r) * q) + p;
  }
  const long long t0 = (long long)(lid % gy) * BM;
  const long long n0 = (long long)(lid / gy) * 256;
  const int nk = K >> 6;

  // ---- A fragment pointers (direct global->reg), clamped rows
  const long long Mm1 = M - 1, Nm1 = N - 1;
  const signed char* pA[MI];
#pragma unroll
  for (int mi = 0; mi < MI; ++mi) {
    long long r = t0 + wavem * (BM / 2) + mi * 16 + lh;
    if (r > Mm1) r = Mm1;
    pA[mi] = A + r * (long long)K + ((lane >> 4) << 4);
  }

  // ---- B staging pointers: 2 x 1KB chunks per wave, global-side XOR
  const signed char* spB[2];
  int dstB[2];
#pragma unroll
  for (int i = 0; i < 2; ++i) {
    const int c = wave * 2 + i;                // 16 chunks = 256 rows
    const int lr = c * 16 + (lane >> 2);
    const int gslot = (((lane & 3) ^ ((lr >> 1) & 3)) << 4);
    long long gr = n0 + lr;
    if (gr > Nm1) gr = Nm1;
    spB[i] = Bw + gr * (long long)K + gslot;
    dstB[i] = c * 1024;
  }

#define STB(sl) do { \
    __builtin_amdgcn_global_load_lds(AS1C(spB[0]), AS3(&smem[(sl) * 16384 + dstB[0]]), 16, 0, 0); spB[0] += 64; \
    __builtin_amdgcn_global_load_lds(AS1C(spB[1]), AS3(&smem[(sl) * 16384 + dstB[1]]), 16, 0, 0); spB[1] += 64; \
  } while (0)

  // ---- B reader offset (XOR involution)
  const int xs = (((lane >> 4) ^ ((lh >> 1) & 3)) << 4);
  const int offB = waven * 4096 + lh * 64 + xs;   // + ni*1024

  v4i acc[MI][4] = {};
  v4i aA[MI], aB[MI], b_[4];

  // ---- prologue: A(0) -> aA; stage B(0),B(1),B(2)
#pragma unroll
  for (int mi = 0; mi < MI; ++mi) { aA[mi] = *(const v4i*)pA[mi]; pA[mi] += 64; }
  STB(0);
  if (nk > 1) STB(1);
  if (nk > 2) STB(2);

#define ITER(T, AU, AL) do { \
    const int T_ = (T); \
    fence_vm(T_ == 0 ? (nk > 2 ? 4 : (nk > 1 ? 2 : 0)) : ((T_ + 2 < nk) ? 2 : 0)); \
    BARRIER(); \
    if (T_ + 1 < nk) { \
      _Pragma("unroll") \
      for (int mi = 0; mi < MI; ++mi) { AL[mi] = *(const v4i*)pA[mi]; pA[mi] += 64; } \
    } \
    if (T_ + 3 < nk) STB((T_ + 3) & 3); \
    { \
      const char* bb = &smem[(T_ & 3) * 16384]; \
      _Pragma("unroll") \
      for (int ni = 0; ni < 4; ++ni) b_[ni] = *(const v4i*)(bb + offB + ni * 1024); \
    } \
    __builtin_amdgcn_s_setprio(1); \
    _Pragma("unroll") \
    for (int mi = 0; mi < MI; ++mi) \
      _Pragma("unroll") \
      for (int ni = 0; ni < 4; ++ni) \
        acc[mi][ni] = __builtin_amdgcn_mfma_i32_16x16x64_i8(AU[mi], b_[ni], acc[mi][ni], 0, 0, 0); \
    __builtin_amdgcn_s_setprio(0); \
  } while (0)

  // nk is even for this problem (50 / 200); generic tail guard anyway
  int t = 0;
  for (; t + 1 < nk; t += 2) {
    ITER(t, aA, aB);
    ITER(t + 1, aB, aA);
  }
  if (t < nk) ITER(t, aA, aB);
#undef ITER
#undef STB

  // ---- epilogue
  long long cidx[4]; float w4[4], bi4[4]; bool cok[4];
#pragma unroll
  for (int ni = 0; ni < 4; ++ni) {
    cidx[ni] = n0 + waven * 64 + ni * 16 + lh;
    cok[ni] = cidx[ni] < N;
    w4[ni] = cok[ni] ? wsc[cidx[ni]] : 0.f;
    bi4[ni] = cok[ni] ? bias[cidx[ni]] : 0.f;
  }
  if (EPI == 0) {
#pragma unroll
    for (int mi = 0; mi < MI; ++mi) {
#pragma unroll
      for (int j = 0; j < 4; ++j) {
        const long long t2 = t0 + wavem * (BM / 2) + mi * 16 + (lane >> 4) * 4 + j;
        const bool valid = t2 < M;
        const float st = valid ? scale_tok[t2] : 0.f;
        float rowmax = 0.f;
#pragma unroll
        for (int ni = 0; ni < 4; ++ni) {
          float v = (float)acc[mi][ni][j] * st * w4[ni] + bi4[ni];
          v = __half2float(__float2half(v));  // fc1 rounds to fp16 (reference)
          const float gl = 0.5f * v * (1.f + erff(v * 0.70710678118654752f));
          rowmax = fmaxf(rowmax, fabsf(gl));
          if (valid && cok[ni]) gout[t2 * (long long)N + cidx[ni]] = __float2half(gl);
        }
#pragma unroll
        for (int m = 1; m < 16; m <<= 1) rowmax = fmaxf(rowmax, __shfl_xor(rowmax, m));
        if (valid && lh == 0) atomicMax(&amax[t2], __float_as_uint(rowmax));
      }
    }
  } else {
#pragma unroll
    for (int mi = 0; mi < MI; ++mi) {
#pragma unroll
      for (int j = 0; j < 4; ++j) {
        const long long t2 = t0 + wavem * (BM / 2) + mi * 16 + (lane >> 4) * 4 + j;
        if (t2 < M) {
          const float am = __uint_as_float(amax[t2]);
          const float st = __half2float(__float2half(am * (1.f / 127.f)));
#pragma unroll
          for (int ni = 0; ni < 4; ++ni) {
            const float v = (float)acc[mi][ni][j] * st * w4[ni] + bi4[ni];
            if (cok[ni]) fout[t2 * (long long)N + cidx[ni]] = __half2float(__float2half(v));
          }
        }
      }
    }
  }
}

// ---------------------------------------------------------------------------
// int32 -> int8 packing for x, w1, w2 (+ zero the amax buffer each call)
// ---------------------------------------------------------------------------
__global__ void pack_all(const int* __restrict__ a, const int* __restrict__ b,
                         const int* __restrict__ c,
                         signed char* __restrict__ pa, signed char* __restrict__ pb,
                         signed char* __restrict__ pc,
                         unsigned int* __restrict__ amax,
                         long long na, long long nb, long long nc, int T) {
  const long long gid = blockIdx.x * (long long)blockDim.x + threadIdx.x;
  if (gid < T) amax[gid] = 0u;
  const long long n4a = na >> 2, n4b = nb >> 2, n4c = nc >> 2;
  const long long tot = n4a + n4b + n4c;
  const long long stride = (long long)gridDim.x * blockDim.x;
  for (long long u = gid; u < tot; u += stride) {
    const int* src; signed char* dst; long long loc;
    if (u < n4a)            { src = a; dst = pa; loc = u; }
    else if (u < n4a + n4b) { src = b; dst = pb; loc = u - n4a; }
    else                    { src = c; dst = pc; loc = u - n4a - n4b; }
    const int4 v = *(const int4*)(src + (loc << 2));
    const unsigned out = (unsigned)(v.x & 0xff) | ((unsigned)(v.y & 0xff) << 8) |
                         ((unsigned)(v.z & 0xff) << 16) | ((unsigned)(v.w & 0xff) << 24);
    *(unsigned*)(dst + (loc << 2)) = out;
  }
}

// ---------------------------------------------------------------------------
// per-token dynamic int8 quantization of the GELU output
// ---------------------------------------------------------------------------
__global__ void gelu_quant(const __half* __restrict__ g, const unsigned int* __restrict__ amax,
                           signed char* __restrict__ q, long long total, int I) {
  const long long nchunk = total >> 3;
  const long long stride = (long long)gridDim.x * blockDim.x;
  for (long long c = blockIdx.x * (long long)blockDim.x + threadIdx.x; c < nchunk; c += stride) {
    const long long base = c << 3;  // 8 elems, never crosses a row (I % 8 == 0)
    const int t = (int)(base / I);
    const float am = __uint_as_float(amax[t]);
    const float s = fmaxf(__half2float(__float2half(am * (1.f / 127.f))), 1e-8f);
    const float inv = 1.f / s;
    const int4 raw = *(const int4*)(g + base);
    const __half2* h2 = (const __half2*)&raw;
    union { signed char b[8]; int2 v; } u;
#pragma unroll
    for (int k = 0; k < 4; ++k) {
      const float2 f = __half22float2(h2[k]);
      const float q0 = fminf(fmaxf(rintf(f.x * inv), -128.f), 127.f);
      const float q1 = fminf(fmaxf(rintf(f.y * inv), -128.f), 127.f);
      u.b[k * 2]     = (signed char)(int)q0;
      u.b[k * 2 + 1] = (signed char)(int)q1;
    }
    *(int2*)(q + base) = u.v;
  }
}

extern "C" void kernel_launch(void* const* d_in, const int* in_sizes, int n_in,
                              void* d_out, int out_size, void* d_ws, size_t ws_size,
                              hipStream_t stream) {
  const int* hs = (const int*)d_in[0];
  const float* scale_in = (const float*)d_in[1];   // fp16 in reference -> f32 buffer
  const int* w1 = (const int*)d_in[2];
  const float* w1s = (const float*)d_in[3];
  const float* b1 = (const float*)d_in[4];
  const int* w2 = (const int*)d_in[5];
  const float* w2s = (const float*)d_in[6];
  const float* b2 = (const float*)d_in[7];

  const int T = in_sizes[1];        // 2050
  const int I = in_sizes[3];        // 12800
  const int H = in_sizes[6];        // 3200

  char* ws = (char*)d_ws;
  unsigned int* amax = (unsigned int*)ws;                    // T u32 (16KB pad)
  signed char* px  = (signed char*)(ws + 16384);             // T*H
  signed char* pw1 = px + (size_t)T * H;                     // I*H
  signed char* pw2 = pw1 + (size_t)I * H;                    // H*I
  __half* gbuf = (__half*)(pw2 + (size_t)H * I);             // T*I fp16
  signed char* qbuf = (signed char*)(gbuf + (size_t)T * I);  // T*I

  const long long nx = (long long)T * H, nw1 = (long long)I * H, nw2 = (long long)H * I;

  pack_all<<<2048, 256, 0, stream>>>(hs, w1, w2, px, pw1, pw2, amax, nx, nw1, nw2, T);

  // fc1: 256x256 tiles, grid 50 x 9 = 450 blocks
  dim3 g1(I / 256, (T + 255) / 256);
  gemm_areg<0, 256><<<g1, 512, 0, stream>>>(px, pw1, T, I, H, scale_in, w1s, b1, gbuf, amax, nullptr);

  gelu_quant<<<2048, 256, 0, stream>>>(gbuf, amax, qbuf, (long long)T * I, I);

  // fc2: 128x256 tiles, grid 13 x 17 = 221 blocks
  dim3 g2((H + 255) / 256, (T + 127) / 128);
  gemm_areg<1, 128><<<g2, 512, 0, stream>>>(qbuf, pw2, T, H, I, nullptr, w2s, b2, nullptr, amax, (float*)d_out);
}

// Round 8
// 379.988 us; speedup vs baseline: 1.7636x; 1.7636x over previous
//
#include <hip/hip_runtime.h>
#include <hip/hip_fp16.h>

typedef int v4i __attribute__((ext_vector_type(4)));

#define AS1C(p) ((const __attribute__((address_space(1))) void*)(p))
#define AS3(p)  ((__attribute__((address_space(3))) void*)(p))

// ---------------------------------------------------------------------------
// Stage a 128-row x 64-byte tile from global (row-major, leading dim ld) into
// LDS via global_load_lds (width 16). 16B slot XOR-swizzled on the GLOBAL
// side; reader applies the same involution. (0 conflicts, r2-r7 verified.)
// ---------------------------------------------------------------------------
__device__ __forceinline__ void stage_tile(const signed char* __restrict__ g, long long ld,
                                           long long rmax, long long r0, int k0,
                                           char* lds, int tid) {
  const int wave = tid >> 6, lane = tid & 63;
#pragma unroll
  for (int p = 0; p < 2; ++p) {
    const int chunk = wave * 2 + p;           // 8 chunks of 1 KiB = 128x64
    const int row = chunk * 16 + (lane >> 2); // 4 lanes per 64B row
    const int slot = lane & 3;
    const int gslot = slot ^ ((row >> 1) & 3);
    long long rg = r0 + row;
    if (rg > rmax) rg = rmax;
    const signed char* src = g + rg * ld + (long long)k0 + gslot * 16;
    char* dst = lds + chunk * 1024;
    __builtin_amdgcn_global_load_lds(AS1C(src), AS3(dst), 16, 0, 0);
  }
}

// ---------------------------------------------------------------------------
// 128x128 int8 GEMM tile, C = A[M,K]*B[N,K]^T, 4 waves (2x2 of 64x64),
// mfma_i32_16x16x64_i8, double-buffered LDS, __syncthreads per K-step.
// TLP-first design: 56 VGPR / 32KB LDS -> 4-5 blocks/CU; inter-block overlap
// hides the per-step drain (r2 evidence: this beat all pipelined variants).
// Column-chunked bijective XCD swizzle for B-panel L2 reuse (r6: -55% FETCH).
// EPI 0: fc1 (dequant+bias -> fp16 -> GELU -> gout fp16 + atomicMax amax)
// EPI 1: fc2 (dequant with fp16(amax/127)+bias -> fp16-rounded f32 out)
// ---------------------------------------------------------------------------
template <int EPI>
__launch_bounds__(256, 4)
__global__ void gemm_i8(const signed char* __restrict__ A, const signed char* __restrict__ Bw,
                        int M, int N, int K,
                        const float* __restrict__ scale_tok, const float* __restrict__ wsc,
                        const float* __restrict__ bias,
                        __half* __restrict__ gout, unsigned int* __restrict__ amax,
                        float* __restrict__ fout) {
  __shared__ __align__(16) char lds[2][2][128 * 64];
  const int tid = threadIdx.x;
  const int lane = tid & 63, wave = tid >> 6;
  const int wrow = (wave >> 1) * 64, wcol = (wave & 1) * 64;

  // column-chunked bijective XCD swizzle: consecutive lid share n0 (B panel)
  const int gy = gridDim.y;
  int lid;
  {
    const int o = blockIdx.y * gridDim.x + blockIdx.x;
    const int nwg = gridDim.x * gy;
    const int q = nwg >> 3, r = nwg & 7;
    const int x = o & 7, p = o >> 3;
    lid = (x < r ? x * (q + 1) : r * (q + 1) + (x - r) * q) + p;
  }
  const long long t0 = (long long)(lid % gy) * 128;
  const long long n0 = (long long)(lid / gy) * 128;

  v4i acc[4][4] = {};

  stage_tile(A, K, (long long)M - 1, t0, 0, lds[0][0], tid);
  stage_tile(Bw, K, (long long)N - 1, n0, 0, lds[0][1], tid);
  __syncthreads();

  const int nk = K >> 6;
  int cur = 0;
  const int srow = lane & 15, sseg = lane >> 4;
  for (int kt = 0; kt < nk; ++kt) {
    if (kt + 1 < nk) {
      stage_tile(A, K, (long long)M - 1, t0, (kt + 1) << 6, lds[cur ^ 1][0], tid);
      stage_tile(Bw, K, (long long)N - 1, n0, (kt + 1) << 6, lds[cur ^ 1][1], tid);
    }
    v4i af[4], bf[4];
#pragma unroll
    for (int mi = 0; mi < 4; ++mi) {
      const int r = wrow + mi * 16 + srow;
      const int sl = sseg ^ ((r >> 1) & 3);
      af[mi] = *(const v4i*)&lds[cur][0][r * 64 + sl * 16];
    }
#pragma unroll
    for (int ni = 0; ni < 4; ++ni) {
      const int r = wcol + ni * 16 + srow;
      const int sl = sseg ^ ((r >> 1) & 3);
      bf[ni] = *(const v4i*)&lds[cur][1][r * 64 + sl * 16];
    }
#pragma unroll
    for (int mi = 0; mi < 4; ++mi)
#pragma unroll
      for (int ni = 0; ni < 4; ++ni)
        acc[mi][ni] = __builtin_amdgcn_mfma_i32_16x16x64_i8(af[mi], bf[ni], acc[mi][ni], 0, 0, 0);
    __syncthreads();
    cur ^= 1;
  }

  if (EPI == 0) {
#pragma unroll
    for (int mi = 0; mi < 4; ++mi) {
#pragma unroll
      for (int j = 0; j < 4; ++j) {
        const long long t = t0 + wrow + mi * 16 + (lane >> 4) * 4 + j;
        const bool valid = (t < M);
        const float st = valid ? scale_tok[t] : 0.f;
        float rowmax = 0.f;
#pragma unroll
        for (int ni = 0; ni < 4; ++ni) {
          const long long c = n0 + wcol + ni * 16 + (lane & 15);
          float v = (float)acc[mi][ni][j] * st * wsc[c] + bias[c];
          v = __half2float(__float2half(v));  // fc1 rounds to fp16 (reference)
          const float gl = 0.5f * v * (1.f + erff(v * 0.70710678118654752f));
          rowmax = fmaxf(rowmax, fabsf(gl));
          if (valid) gout[t * (long long)N + c] = __float2half(gl);
        }
#pragma unroll
        for (int m = 1; m < 16; m <<= 1) rowmax = fmaxf(rowmax, __shfl_xor(rowmax, m));
        if (valid && (lane & 15) == 0) atomicMax(&amax[t], __float_as_uint(rowmax));
      }
    }
  } else {
#pragma unroll
    for (int mi = 0; mi < 4; ++mi) {
#pragma unroll
      for (int j = 0; j < 4; ++j) {
        const long long t = t0 + wrow + mi * 16 + (lane >> 4) * 4 + j;
        if (t < M) {
          const float am = __uint_as_float(amax[t]);
          const float st = __half2float(__float2half(am * (1.f / 127.f)));
#pragma unroll
          for (int ni = 0; ni < 4; ++ni) {
            const long long c = n0 + wcol + ni * 16 + (lane & 15);
            const float v = (float)acc[mi][ni][j] * st * wsc[c] + bias[c];
            fout[t * (long long)N + c] = __half2float(__float2half(v));
          }
        }
      }
    }
  }
}

// ---------------------------------------------------------------------------
// int32 -> int8 packing for x, w1, w2 (+ zero the amax buffer each call)
// ---------------------------------------------------------------------------
__global__ void pack_all(const int* __restrict__ a, const int* __restrict__ b,
                         const int* __restrict__ c,
                         signed char* __restrict__ pa, signed char* __restrict__ pb,
                         signed char* __restrict__ pc,
                         unsigned int* __restrict__ amax,
                         long long na, long long nb, long long nc, int T) {
  const long long gid = blockIdx.x * (long long)blockDim.x + threadIdx.x;
  if (gid < T) amax[gid] = 0u;
  const long long n4a = na >> 2, n4b = nb >> 2, n4c = nc >> 2;
  const long long tot = n4a + n4b + n4c;
  const long long stride = (long long)gridDim.x * blockDim.x;
  for (long long u = gid; u < tot; u += stride) {
    const int* src; signed char* dst; long long loc;
    if (u < n4a)            { src = a; dst = pa; loc = u; }
    else if (u < n4a + n4b) { src = b; dst = pb; loc = u - n4a; }
    else                    { src = c; dst = pc; loc = u - n4a - n4b; }
    const int4 v = *(const int4*)(src + (loc << 2));
    const unsigned out = (unsigned)(v.x & 0xff) | ((unsigned)(v.y & 0xff) << 8) |
                         ((unsigned)(v.z & 0xff) << 16) | ((unsigned)(v.w & 0xff) << 24);
    *(unsigned*)(dst + (loc << 2)) = out;
  }
}

// ---------------------------------------------------------------------------
// per-token dynamic int8 quantization of the GELU output
// ---------------------------------------------------------------------------
__global__ void gelu_quant(const __half* __restrict__ g, const unsigned int* __restrict__ amax,
                           signed char* __restrict__ q, long long total, int I) {
  const long long nchunk = total >> 3;
  const long long stride = (long long)gridDim.x * blockDim.x;
  for (long long c = blockIdx.x * (long long)blockDim.x + threadIdx.x; c < nchunk; c += stride) {
    const long long base = c << 3;  // 8 elems, never crosses a row (I % 8 == 0)
    const int t = (int)(base / I);
    const float am = __uint_as_float(amax[t]);
    const float s = fmaxf(__half2float(__float2half(am * (1.f / 127.f))), 1e-8f);
    const float inv = 1.f / s;
    const int4 raw = *(const int4*)(g + base);
    const __half2* h2 = (const __half2*)&raw;
    union { signed char b[8]; int2 v; } u;
#pragma unroll
    for (int k = 0; k < 4; ++k) {
      const float2 f = __half22float2(h2[k]);
      const float q0 = fminf(fmaxf(rintf(f.x * inv), -128.f), 127.f);
      const float q1 = fminf(fmaxf(rintf(f.y * inv), -128.f), 127.f);
      u.b[k * 2]     = (signed char)(int)q0;
      u.b[k * 2 + 1] = (signed char)(int)q1;
    }
    *(int2*)(q + base) = u.v;
  }
}

extern "C" void kernel_launch(void* const* d_in, const int* in_sizes, int n_in,
                              void* d_out, int out_size, void* d_ws, size_t ws_size,
                              hipStream_t stream) {
  const int* hs = (const int*)d_in[0];
  const float* scale_in = (const float*)d_in[1];   // fp16 in reference -> f32 buffer
  const int* w1 = (const int*)d_in[2];
  const float* w1s = (const float*)d_in[3];
  const float* b1 = (const float*)d_in[4];
  const int* w2 = (const int*)d_in[5];
  const float* w2s = (const float*)d_in[6];
  const float* b2 = (const float*)d_in[7];

  const int T = in_sizes[1];        // 2050
  const int I = in_sizes[3];        // 12800
  const int H = in_sizes[6];        // 3200

  char* ws = (char*)d_ws;
  unsigned int* amax = (unsigned int*)ws;                    // T u32 (16KB pad)
  signed char* px  = (signed char*)(ws + 16384);             // T*H
  signed char* pw1 = px + (size_t)T * H;                     // I*H
  signed char* pw2 = pw1 + (size_t)I * H;                    // H*I
  __half* gbuf = (__half*)(pw2 + (size_t)H * I);             // T*I fp16
  signed char* qbuf = (signed char*)(gbuf + (size_t)T * I);  // T*I

  const long long nx = (long long)T * H, nw1 = (long long)I * H, nw2 = (long long)H * I;

  pack_all<<<2048, 256, 0, stream>>>(hs, w1, w2, px, pw1, pw2, amax, nx, nw1, nw2, T);

  // fc1: 128x128 tiles, grid 100 x 17 = 1700 blocks
  dim3 g1(I / 128, (T + 127) / 128);
  gemm_i8<0><<<g1, 256, 0, stream>>>(px, pw1, T, I, H, scale_in, w1s, b1, gbuf, amax, nullptr);

  gelu_quant<<<2048, 256, 0, stream>>>(gbuf, amax, qbuf, (long long)T * I, I);

  // fc2: 128x128 tiles, grid 25 x 17 = 425 blocks
  dim3 g2(H / 128, (T + 127) / 128);
  gemm_i8<1><<<g2, 256, 0, stream>>>(qbuf, pw2, T, H, I, nullptr, w2s, b2, nullptr, amax, (float*)d_out);
}